// Round 1
// baseline (422.772 us; speedup 1.0000x reference)
//
#include <hip/hip_runtime.h>
#include <hip/hip_bf16.h>

#define BB 16
#define SS 2048
#define DD 2048
#define HH 16
#define HDIM 128
#define PAD_ID 50257
#define LN_EPS 1e-5f

// ---------- block reduction helpers (256 threads = 4 waves) ----------
__device__ __forceinline__ float block_sum256(float v, float* s4) {
    #pragma unroll
    for (int m = 32; m >= 1; m >>= 1) v += __shfl_xor(v, m, 64);
    __syncthreads();
    if ((threadIdx.x & 63) == 0) s4[threadIdx.x >> 6] = v;
    __syncthreads();
    return s4[0] + s4[1] + s4[2] + s4[3];
}
__device__ __forceinline__ float block_max256(float v, float* s4) {
    #pragma unroll
    for (int m = 32; m >= 1; m >>= 1) v = fmaxf(v, __shfl_xor(v, m, 64));
    __syncthreads();
    if ((threadIdx.x & 63) == 0) s4[threadIdx.x >> 6] = v;
    __syncthreads();
    return fmaxf(fmaxf(s4[0], s4[1]), fmaxf(s4[2], s4[3]));
}

// ---------- K0a: last non-pad index per batch ----------
__global__ __launch_bounds__(256) void k_idx(const int* __restrict__ ids, int* __restrict__ idx) {
    int b = blockIdx.x;
    const int* row = ids + (size_t)b * SS;
    int t = threadIdx.x;
    int best = -1;
    for (int s = t; s < SS; s += 256)
        if (row[s] != PAD_ID) best = s;   // ascending -> ends at max in this stride set
    __shared__ int sm[256];
    sm[t] = best;
    __syncthreads();
    for (int off = 128; off > 0; off >>= 1) {
        if (t < off) sm[t] = max(sm[t], sm[t + off]);
        __syncthreads();
    }
    if (t == 0) idx[b] = (sm[0] < 0) ? 0 : sm[0];
}

// ---------- K0b: layernorm the selected row -> xlast[B,D] ----------
__global__ __launch_bounds__(256) void k_xlast(const float* __restrict__ hid, const int* __restrict__ idx,
                                               const float* __restrict__ g, const float* __restrict__ be,
                                               float* __restrict__ xlast) {
    int b = blockIdx.x, tid = threadIdx.x;
    __shared__ float s4[4];
    const float4* row4 = (const float4*)(hid + ((size_t)b * SS + idx[b]) * DD);
    float4 v0 = row4[tid], v1 = row4[tid + 256];
    float s  = v0.x + v0.y + v0.z + v0.w + v1.x + v1.y + v1.z + v1.w;
    float sq = v0.x*v0.x + v0.y*v0.y + v0.z*v0.z + v0.w*v0.w
             + v1.x*v1.x + v1.y*v1.y + v1.z*v1.z + v1.w*v1.w;
    s  = block_sum256(s, s4);
    sq = block_sum256(sq, s4);
    float mu = s * (1.0f / DD);
    float rstd = rsqrtf(sq * (1.0f / DD) - mu * mu + LN_EPS);
    const float4* g4 = (const float4*)g;
    const float4* b4 = (const float4*)be;
    float4 ga = g4[tid], gb = g4[tid + 256], ba = b4[tid], bb = b4[tid + 256];
    float4 o0, o1;
    o0.x = (v0.x - mu) * rstd * ga.x + ba.x;  o0.y = (v0.y - mu) * rstd * ga.y + ba.y;
    o0.z = (v0.z - mu) * rstd * ga.z + ba.z;  o0.w = (v0.w - mu) * rstd * ga.w + ba.w;
    o1.x = (v1.x - mu) * rstd * gb.x + bb.x;  o1.y = (v1.y - mu) * rstd * gb.y + bb.y;
    o1.z = (v1.z - mu) * rstd * gb.z + bb.z;  o1.w = (v1.w - mu) * rstd * gb.w + bb.w;
    ((float4*)(xlast + (size_t)b * DD))[tid]       = o0;
    ((float4*)(xlast + (size_t)b * DD))[tid + 256] = o1;
}

// ---------- init: dst[i] = bias[i % mod] (mod power of 2) ----------
__global__ __launch_bounds__(256) void k_init_bias(float* __restrict__ dst, const float* __restrict__ bias,
                                                   int n, int mod) {
    int i = blockIdx.x * 256 + threadIdx.x;
    if (i < n) dst[i] = bias[i & (mod - 1)];
}

// ---------- Kq: q[b,p] += sum_d xlast[b,d]*wq[d,p]  (grid 8 ptiles x 8 dchunks) ----------
__global__ __launch_bounds__(256) void k_q(const float* __restrict__ xlast, const float* __restrict__ wq,
                                           float* __restrict__ q) {
    int ptile = blockIdx.x, dch = blockIdx.y, tid = threadIdx.x;
    __shared__ float xs[16][256];
    #pragma unroll
    for (int k = 0; k < 4; k++) {
        int f4 = tid + k * 256;            // 1024 float4 = 16 x 64
        int b = f4 >> 6, c4 = f4 & 63;
        *(float4*)&xs[b][c4 * 4] = *(const float4*)&xlast[(size_t)b * DD + dch * 256 + c4 * 4];
    }
    __syncthreads();
    int p = ptile * 256 + tid;
    float acc[16];
    #pragma unroll
    for (int b = 0; b < 16; b++) acc[b] = 0.f;
    for (int dd = 0; dd < 256; dd++) {
        float wqv = wq[(size_t)(dch * 256 + dd) * DD + p];
        #pragma unroll
        for (int b = 0; b < 16; b++) acc[b] = fmaf(xs[b][dd], wqv, acc[b]);
    }
    #pragma unroll
    for (int b = 0; b < 16; b++) atomicAdd(&q[(size_t)b * DD + p], acc[b]);
}

// ---------- Kt: t[b,h,d] = sum_j wk[d, h*128+j]*q[b, h*128+j]; tg = t*g[d] ----------
__global__ __launch_bounds__(256) void k_t(const float* __restrict__ wk, const float* __restrict__ q,
                                           const float* __restrict__ g, float* __restrict__ t_out,
                                           float* __restrict__ tg_out) {
    int d = blockIdx.x, tid = threadIdx.x;
    __shared__ float wkl[16 * 132];        // padded per head to avoid bank conflicts
    #pragma unroll
    for (int k = 0; k < 2; k++) {
        int f4 = tid + k * 256;            // 512 float4 = 2048 floats
        int h = f4 >> 5, j4 = f4 & 31;
        *(float4*)&wkl[h * 132 + j4 * 4] = *(const float4*)&wk[(size_t)d * DD + h * 128 + j4 * 4];
    }
    __syncthreads();
    int b = tid >> 4, h = tid & 15;
    const float4* q4 = (const float4*)(q + (size_t)b * DD + h * 128);
    float acc = 0.f;
    #pragma unroll
    for (int j4 = 0; j4 < 32; j4++) {
        float4 qv = q4[j4];
        float4 wv4 = *(const float4*)&wkl[h * 132 + j4 * 4];
        acc = fmaf(qv.x, wv4.x, fmaf(qv.y, wv4.y, fmaf(qv.z, wv4.z, fmaf(qv.w, wv4.w, acc))));
    }
    size_t o = (size_t)(b * 16 + h) * DD + d;
    t_out[o] = acc;
    tg_out[o] = acc * g[d];
}

// ---------- KG: G1[bh]=sum_d tg ; wconst[bh]=sum_d beta*t + sum_j bk*q ----------
__global__ __launch_bounds__(256) void k_G(const float* __restrict__ t_in, const float* __restrict__ tg_in,
                                           const float* __restrict__ q, const float* __restrict__ lnb,
                                           const float* __restrict__ bk, float* __restrict__ G1,
                                           float* __restrict__ wconst) {
    int bh = blockIdx.x, tid = threadIdx.x;
    int b = bh >> 4, h = bh & 15;
    __shared__ float s4[4];
    const float4* tg4 = (const float4*)(tg_in + (size_t)bh * DD);
    const float4* t4  = (const float4*)(t_in + (size_t)bh * DD);
    const float4* lb4 = (const float4*)lnb;
    float g1p = 0.f, g2p = 0.f;
    #pragma unroll
    for (int k = 0; k < 2; k++) {
        int f = tid + k * 256;
        float4 a = tg4[f];
        g1p += a.x + a.y + a.z + a.w;
        float4 tv = t4[f];
        float4 bv = lb4[f];
        g2p = fmaf(tv.x, bv.x, fmaf(tv.y, bv.y, fmaf(tv.z, bv.z, fmaf(tv.w, bv.w, g2p))));
    }
    float cp = 0.f;
    if (tid < 128) cp = bk[h * 128 + tid] * q[(size_t)b * DD + h * 128 + tid];
    float G1v = block_sum256(g1p, s4);
    float rest = block_sum256(g2p + cp, s4);
    if (tid == 0) { G1[bh] = G1v; wconst[bh] = rest; }
}

// ---------- K1: fused LN-stats + logits.  grid (B, S/64), 256 threads ----------
// w[b,h,s] = rstd_s*(sum_d hid*tg[b,h,d] - mu_s*G1[b,h]) + wconst[b,h]
__global__ __launch_bounds__(256) void k_logits(const float* __restrict__ hid, const float* __restrict__ tg,
                                                const float* __restrict__ G1, const float* __restrict__ wcst,
                                                float* __restrict__ wout, float* __restrict__ mu_out,
                                                float* __restrict__ rstd_out) {
    __shared__ float xl[64][128];
    __shared__ float tl[16][128];
    int b = blockIdx.x, st = blockIdx.y, tid = threadIdx.x;
    int rg = tid >> 4, qd = tid & 15;
    const size_t base = ((size_t)b * SS + st * 64) * DD;

    float4 xr[8], tr[2];
    auto load_chunk = [&](int c) {
        int d0 = c * 128;
        #pragma unroll
        for (int k = 0; k < 8; k++) {
            int f = tid + k * 256;          // float4 units: 2048 = 64 rows x 32
            int row = f >> 5, c4 = f & 31;
            xr[k] = *(const float4*)&hid[base + (size_t)row * DD + d0 + c4 * 4];
        }
        #pragma unroll
        for (int k = 0; k < 2; k++) {
            int f = tid + k * 256;          // 512 = 16 heads x 32
            int h = f >> 5, c4 = f & 31;
            tr[k] = *(const float4*)&tg[(size_t)(b * 16 + h) * DD + d0 + c4 * 4];
        }
    };
    load_chunk(0);

    float raw[4][16];
    float sum[4], ssq[4];
    #pragma unroll
    for (int r = 0; r < 4; r++) {
        sum[r] = 0.f; ssq[r] = 0.f;
        #pragma unroll
        for (int hh = 0; hh < 16; hh++) raw[r][hh] = 0.f;
    }

    for (int c = 0; c < 16; c++) {
        __syncthreads();
        #pragma unroll
        for (int k = 0; k < 8; k++) { int f = tid + k * 256; *(float4*)&xl[f >> 5][(f & 31) * 4] = xr[k]; }
        #pragma unroll
        for (int k = 0; k < 2; k++) { int f = tid + k * 256; *(float4*)&tl[f >> 5][(f & 31) * 4] = tr[k]; }
        __syncthreads();
        if (c + 1 < 16) load_chunk(c + 1);   // prefetch overlaps compute below

        #pragma unroll
        for (int i4 = 0; i4 < 2; i4++) {
            const int dd = i4 * 64 + qd * 4;
            float4 x0 = *(const float4*)&xl[rg * 4 + 0][dd];
            float4 x1 = *(const float4*)&xl[rg * 4 + 1][dd];
            float4 x2 = *(const float4*)&xl[rg * 4 + 2][dd];
            float4 x3 = *(const float4*)&xl[rg * 4 + 3][dd];
            sum[0] += x0.x + x0.y + x0.z + x0.w;
            sum[1] += x1.x + x1.y + x1.z + x1.w;
            sum[2] += x2.x + x2.y + x2.z + x2.w;
            sum[3] += x3.x + x3.y + x3.z + x3.w;
            ssq[0] = fmaf(x0.x, x0.x, fmaf(x0.y, x0.y, fmaf(x0.z, x0.z, fmaf(x0.w, x0.w, ssq[0]))));
            ssq[1] = fmaf(x1.x, x1.x, fmaf(x1.y, x1.y, fmaf(x1.z, x1.z, fmaf(x1.w, x1.w, ssq[1]))));
            ssq[2] = fmaf(x2.x, x2.x, fmaf(x2.y, x2.y, fmaf(x2.z, x2.z, fmaf(x2.w, x2.w, ssq[2]))));
            ssq[3] = fmaf(x3.x, x3.x, fmaf(x3.y, x3.y, fmaf(x3.z, x3.z, fmaf(x3.w, x3.w, ssq[3]))));
            #pragma unroll
            for (int hh = 0; hh < 16; hh++) {
                float4 tv = *(const float4*)&tl[hh][dd];
                raw[0][hh] = fmaf(x0.x, tv.x, fmaf(x0.y, tv.y, fmaf(x0.z, tv.z, fmaf(x0.w, tv.w, raw[0][hh]))));
                raw[1][hh] = fmaf(x1.x, tv.x, fmaf(x1.y, tv.y, fmaf(x1.z, tv.z, fmaf(x1.w, tv.w, raw[1][hh]))));
                raw[2][hh] = fmaf(x2.x, tv.x, fmaf(x2.y, tv.y, fmaf(x2.z, tv.z, fmaf(x2.w, tv.w, raw[2][hh]))));
                raw[3][hh] = fmaf(x3.x, tv.x, fmaf(x3.y, tv.y, fmaf(x3.z, tv.z, fmaf(x3.w, tv.w, raw[3][hh]))));
            }
        }
    }

    // butterfly-reduce stats over the 16 qd lanes (lane bits 0..3)
    #pragma unroll
    for (int m = 1; m < 16; m <<= 1) {
        #pragma unroll
        for (int r = 0; r < 4; r++) {
            sum[r] += __shfl_xor(sum[r], m, 64);
            ssq[r] += __shfl_xor(ssq[r], m, 64);
        }
    }

    float g1 = G1[b * 16 + qd];
    float wc = wcst[b * 16 + qd];
    float* red = &xl[0][0];                 // reuse LDS: 16*16*17 = 4352 floats
    __syncthreads();
    for (int rr = 0; rr < 4; rr++) {
        #pragma unroll
        for (int hh = 0; hh < 16; hh++) red[(qd * 16 + rg) * 17 + hh] = raw[rr][hh];
        __syncthreads();
        float tot = 0.f;
        #pragma unroll
        for (int qq = 0; qq < 16; qq++) tot += red[(qq * 16 + rg) * 17 + qd];
        int s = st * 64 + rg * 4 + rr;
        float mu = sum[rr] * (1.0f / DD);
        float var = ssq[rr] * (1.0f / DD) - mu * mu;
        float rstd = rsqrtf(var + LN_EPS);
        wout[(size_t)(b * 16 + qd) * SS + s] = rstd * (tot - mu * g1) + wc;
        if (qd == 0) { mu_out[(size_t)b * SS + s] = mu; rstd_out[(size_t)b * SS + s] = rstd; }
        __syncthreads();
    }
}

// ---------- K2: softmax over s per (b,h); coef = p*rstd; M = sum coef*mu ----------
__global__ __launch_bounds__(256) void k_softmax(const float* __restrict__ wlog, const float* __restrict__ muA,
                                                 const float* __restrict__ rsA, float* __restrict__ coef,
                                                 float* __restrict__ Mout) {
    int bh = blockIdx.x, tid = threadIdx.x;
    int b = bh >> 4;
    __shared__ float s4[4];
    const float4* w4 = (const float4*)(wlog + (size_t)bh * SS);
    float4 v0 = w4[tid], v1 = w4[tid + 256];
    float mx = fmaxf(fmaxf(fmaxf(v0.x, v0.y), fmaxf(v0.z, v0.w)),
                     fmaxf(fmaxf(v1.x, v1.y), fmaxf(v1.z, v1.w)));
    mx = block_max256(mx, s4);
    float4 e0, e1;
    e0.x = __expf(v0.x - mx); e0.y = __expf(v0.y - mx); e0.z = __expf(v0.z - mx); e0.w = __expf(v0.w - mx);
    e1.x = __expf(v1.x - mx); e1.y = __expf(v1.y - mx); e1.z = __expf(v1.z - mx); e1.w = __expf(v1.w - mx);
    float ssum = e0.x + e0.y + e0.z + e0.w + e1.x + e1.y + e1.z + e1.w;
    ssum = block_sum256(ssum, s4);
    float inv = 1.0f / ssum;
    const float4* r4 = (const float4*)(rsA + (size_t)b * SS);
    const float4* m4 = (const float4*)(muA + (size_t)b * SS);
    float4 ra = r4[tid], rb = r4[tid + 256], ma = m4[tid], mb = m4[tid + 256];
    float4 c0, c1;
    c0.x = e0.x * inv * ra.x; c0.y = e0.y * inv * ra.y; c0.z = e0.z * inv * ra.z; c0.w = e0.w * inv * ra.w;
    c1.x = e1.x * inv * rb.x; c1.y = e1.y * inv * rb.y; c1.z = e1.z * inv * rb.z; c1.w = e1.w * inv * rb.w;
    ((float4*)(coef + (size_t)bh * SS))[tid] = c0;
    ((float4*)(coef + (size_t)bh * SS))[tid + 256] = c1;
    float Mp = c0.x * ma.x + c0.y * ma.y + c0.z * ma.z + c0.w * ma.w
             + c1.x * mb.x + c1.y * mb.y + c1.z * mb.z + c1.w * mb.w;
    Mp = block_sum256(Mp, s4);
    if (tid == 0) Mout[bh] = Mp;
}

// ---------- K3: Apart[ch][b][h][d] = sum_{s in chunk} coef[b,h,s]*hid[b,s,d] ----------
__global__ __launch_bounds__(256) void k_pv(const float* __restrict__ hid, const float* __restrict__ coef,
                                            float* __restrict__ Apart) {
    int b = blockIdx.x, dt = blockIdx.y, ch = blockIdx.z, tid = threadIdx.x;
    __shared__ float cl[16][128];
    int s0 = ch * 128;
    #pragma unroll
    for (int k = 0; k < 2; k++) {
        int f4 = tid + k * 256;             // 512 float4 = 16 heads x 32
        int h = f4 >> 5, s4i = f4 & 31;
        *(float4*)&cl[h][s4i * 4] = *(const float4*)&coef[(size_t)(b * 16 + h) * SS + s0 + s4i * 4];
    }
    __syncthreads();
    int d0 = dt * 1024 + tid * 4;
    float4 acc[16];
    #pragma unroll
    for (int h = 0; h < 16; h++) acc[h] = make_float4(0.f, 0.f, 0.f, 0.f);
    const float* hb = hid + ((size_t)b * SS + s0) * DD + d0;
    for (int sl = 0; sl < 128; sl += 2) {
        float4 x0 = *(const float4*)(hb + (size_t)sl * DD);
        float4 x1 = *(const float4*)(hb + (size_t)(sl + 1) * DD);
        #pragma unroll
        for (int h = 0; h < 16; h++) {
            float c0 = cl[h][sl], c1 = cl[h][sl + 1];
            acc[h].x = fmaf(c0, x0.x, fmaf(c1, x1.x, acc[h].x));
            acc[h].y = fmaf(c0, x0.y, fmaf(c1, x1.y, acc[h].y));
            acc[h].z = fmaf(c0, x0.z, fmaf(c1, x1.z, acc[h].z));
            acc[h].w = fmaf(c0, x0.w, fmaf(c1, x1.w, acc[h].w));
        }
    }
    #pragma unroll
    for (int h = 0; h < 16; h++)
        *(float4*)&Apart[(((size_t)ch * 16 + b) * 16 + h) * DD + d0] = acc[h];
}

// ---------- K3b: A = sum over 16 chunks of Apart ----------
__global__ __launch_bounds__(256) void k_red(const float* __restrict__ Apart, float* __restrict__ A) {
    size_t i4 = (size_t)blockIdx.x * 256 + threadIdx.x;   // float4 index, total 131072
    const float4* ap = (const float4*)Apart;
    float4 acc = make_float4(0.f, 0.f, 0.f, 0.f);
    #pragma unroll
    for (int c = 0; c < 16; c++) {
        float4 v = ap[(size_t)c * 131072 + i4];
        acc.x += v.x; acc.y += v.y; acc.z += v.z; acc.w += v.w;
    }
    ((float4*)A)[i4] = acc;
}

// ---------- K4a: attn[b, h*128+j] += sum_d y[b,h,d]*wv[d, h*128+j] ----------
__global__ __launch_bounds__(256) void k_attnv(const float* __restrict__ A, const float* __restrict__ M,
                                               const float* __restrict__ g, const float* __restrict__ be,
                                               const float* __restrict__ wv, float* __restrict__ attn) {
    int h = blockIdx.x, dc = blockIdx.y, tid = threadIdx.x;
    __shared__ float yl[16][128];
    int d0 = dc * 128;
    #pragma unroll
    for (int k = 0; k < 2; k++) {
        int f4 = tid + k * 256;             // 512 float4 = 16 b x 32
        int b = f4 >> 5, c4 = f4 & 31;
        float4 a4 = *(const float4*)&A[(size_t)(b * 16 + h) * DD + d0 + c4 * 4];
        float4 g4 = *(const float4*)&g[d0 + c4 * 4];
        float4 b4 = *(const float4*)&be[d0 + c4 * 4];
        float m = M[b * 16 + h];
        float4 y;
        y.x = g4.x * (a4.x - m) + b4.x;  y.y = g4.y * (a4.y - m) + b4.y;
        y.z = g4.z * (a4.z - m) + b4.z;  y.w = g4.w * (a4.w - m) + b4.w;
        *(float4*)&yl[b][c4 * 4] = y;
    }
    __syncthreads();
    int j = tid & 127, h2 = tid >> 7;
    float acc[16];
    #pragma unroll
    for (int b = 0; b < 16; b++) acc[b] = 0.f;
    for (int dl = 0; dl < 64; dl++) {
        int dd = h2 * 64 + dl;
        float wvv = wv[(size_t)(d0 + dd) * DD + h * 128 + j];
        #pragma unroll
        for (int b = 0; b < 16; b++) acc[b] = fmaf(yl[b][dd], wvv, acc[b]);
    }
    #pragma unroll
    for (int b = 0; b < 16; b++) atomicAdd(&attn[(size_t)b * DD + h * 128 + j], acc[b]);
}

// ---------- K4b: out[b,p] += sum_c attn[b,c]*wo[c,p] ----------
__global__ __launch_bounds__(256) void k_out(const float* __restrict__ attn, const float* __restrict__ wo,
                                             float* __restrict__ out) {
    int ptile = blockIdx.x, cch = blockIdx.y, tid = threadIdx.x;
    __shared__ float al[16][128];
    int c0 = cch * 128;
    #pragma unroll
    for (int k = 0; k < 2; k++) {
        int f4 = tid + k * 256;
        int b = f4 >> 5, c4 = f4 & 31;
        *(float4*)&al[b][c4 * 4] = *(const float4*)&attn[(size_t)b * DD + c0 + c4 * 4];
    }
    __syncthreads();
    int p = ptile * 256 + tid;
    float acc[16];
    #pragma unroll
    for (int b = 0; b < 16; b++) acc[b] = 0.f;
    for (int cc = 0; cc < 128; cc++) {
        float wov = wo[(size_t)(c0 + cc) * DD + p];
        #pragma unroll
        for (int b = 0; b < 16; b++) acc[b] = fmaf(al[b][cc], wov, acc[b]);
    }
    #pragma unroll
    for (int b = 0; b < 16; b++) atomicAdd(&out[(size_t)b * DD + p], acc[b]);
}

extern "C" void kernel_launch(void* const* d_in, const int* in_sizes, int n_in,
                              void* d_out, int out_size, void* d_ws, size_t ws_size,
                              hipStream_t stream) {
    const float* hid = (const float*)d_in[0];
    const int*   ids = (const int*)d_in[1];
    const float* lnw = (const float*)d_in[2];
    const float* lnb = (const float*)d_in[3];
    const float* wq  = (const float*)d_in[4];
    const float* bq  = (const float*)d_in[5];
    const float* wk  = (const float*)d_in[6];
    const float* bk  = (const float*)d_in[7];
    const float* wv  = (const float*)d_in[8];
    const float* bv  = (const float*)d_in[9];
    const float* wo  = (const float*)d_in[10];
    const float* bo  = (const float*)d_in[11];
    float* out = (float*)d_out;

    float* ws = (float*)d_ws;
    int*   idx   = (int*)ws;                     // 16 (padded to 16 floats)
    float* xlast = ws + 16;                      // 32768
    float* q     = xlast + 32768;                // 32768
    float* t     = q + 32768;                    // 524288
    float* tg    = t + 524288;                   // 524288
    float* G1    = tg + 524288;                  // 256
    float* wcst  = G1 + 256;                     // 256
    float* wlog  = wcst + 256;                   // 524288
    float* muA   = wlog + 524288;                // 32768
    float* rsA   = muA + 32768;                  // 32768
    float* coef  = rsA + 32768;                  // 524288
    float* Mbh   = coef + 524288;                // 256
    float* Abh   = Mbh + 256;                    // 524288
    float* attn  = Abh + 524288;                 // 32768
    float* Apart = attn + 32768;                 // 16*524288 = 8388608

    k_idx<<<16, 256, 0, stream>>>(ids, idx);
    k_xlast<<<16, 256, 0, stream>>>(hid, idx, lnw, lnb, xlast);
    k_init_bias<<<128, 256, 0, stream>>>(q, bq, 32768, DD);
    k_q<<<dim3(8, 8), 256, 0, stream>>>(xlast, wq, q);
    k_t<<<2048, 256, 0, stream>>>(wk, q, lnw, t, tg);
    k_G<<<256, 256, 0, stream>>>(t, tg, q, lnb, bk, G1, wcst);
    k_logits<<<dim3(16, 32), 256, 0, stream>>>(hid, tg, G1, wcst, wlog, muA, rsA);
    k_softmax<<<256, 256, 0, stream>>>(wlog, muA, rsA, coef, Mbh);
    k_pv<<<dim3(16, 2, 16), 256, 0, stream>>>(hid, coef, Apart);
    k_red<<<512, 256, 0, stream>>>(Apart, Abh);
    k_init_bias<<<128, 256, 0, stream>>>(attn, bv, 32768, DD);
    k_attnv<<<dim3(16, 16), 256, 0, stream>>>(Abh, Mbh, lnw, lnb, wv, attn);
    k_init_bias<<<128, 256, 0, stream>>>(out, bo, 32768, DD);
    k_out<<<dim3(8, 16), 256, 0, stream>>>(attn, wo, out);
}

// Round 2
// 307.085 us; speedup vs baseline: 1.3767x; 1.3767x over previous
//
#include <hip/hip_runtime.h>
#include <hip/hip_bf16.h>

#define BB 16
#define SS 2048
#define DD 2048
#define HH 16
#define HDIM 128
#define PAD_ID 50257
#define LN_EPS 1e-5f

// ---------- block reduction helpers (256 threads = 4 waves) ----------
__device__ __forceinline__ float block_sum256(float v, float* s4) {
    #pragma unroll
    for (int m = 32; m >= 1; m >>= 1) v += __shfl_xor(v, m, 64);
    __syncthreads();
    if ((threadIdx.x & 63) == 0) s4[threadIdx.x >> 6] = v;
    __syncthreads();
    return s4[0] + s4[1] + s4[2] + s4[3];
}
__device__ __forceinline__ float block_max256(float v, float* s4) {
    #pragma unroll
    for (int m = 32; m >= 1; m >>= 1) v = fmaxf(v, __shfl_xor(v, m, 64));
    __syncthreads();
    if ((threadIdx.x & 63) == 0) s4[threadIdx.x >> 6] = v;
    __syncthreads();
    return fmaxf(fmaxf(s4[0], s4[1]), fmaxf(s4[2], s4[3]));
}

// ---------- K0a: last non-pad index per batch ----------
__global__ __launch_bounds__(256) void k_idx(const int* __restrict__ ids, int* __restrict__ idx) {
    int b = blockIdx.x;
    const int* row = ids + (size_t)b * SS;
    int t = threadIdx.x;
    int best = -1;
    for (int s = t; s < SS; s += 256)
        if (row[s] != PAD_ID) best = s;
    __shared__ int sm[256];
    sm[t] = best;
    __syncthreads();
    for (int off = 128; off > 0; off >>= 1) {
        if (t < off) sm[t] = max(sm[t], sm[t + off]);
        __syncthreads();
    }
    if (t == 0) idx[b] = (sm[0] < 0) ? 0 : sm[0];
}

// ---------- K0b: layernorm the selected row -> xlast[B,D] ----------
__global__ __launch_bounds__(256) void k_xlast(const float* __restrict__ hid, const int* __restrict__ idx,
                                               const float* __restrict__ g, const float* __restrict__ be,
                                               float* __restrict__ xlast) {
    int b = blockIdx.x, tid = threadIdx.x;
    __shared__ float s4[4];
    const float4* row4 = (const float4*)(hid + ((size_t)b * SS + idx[b]) * DD);
    float4 v0 = row4[tid], v1 = row4[tid + 256];
    float s  = v0.x + v0.y + v0.z + v0.w + v1.x + v1.y + v1.z + v1.w;
    float sq = v0.x*v0.x + v0.y*v0.y + v0.z*v0.z + v0.w*v0.w
             + v1.x*v1.x + v1.y*v1.y + v1.z*v1.z + v1.w*v1.w;
    s  = block_sum256(s, s4);
    sq = block_sum256(sq, s4);
    float mu = s * (1.0f / DD);
    float rstd = rsqrtf(sq * (1.0f / DD) - mu * mu + LN_EPS);
    const float4* g4 = (const float4*)g;
    const float4* b4 = (const float4*)be;
    float4 ga = g4[tid], gb = g4[tid + 256], ba = b4[tid], bb = b4[tid + 256];
    float4 o0, o1;
    o0.x = (v0.x - mu) * rstd * ga.x + ba.x;  o0.y = (v0.y - mu) * rstd * ga.y + ba.y;
    o0.z = (v0.z - mu) * rstd * ga.z + ba.z;  o0.w = (v0.w - mu) * rstd * ga.w + ba.w;
    o1.x = (v1.x - mu) * rstd * gb.x + bb.x;  o1.y = (v1.y - mu) * rstd * gb.y + bb.y;
    o1.z = (v1.z - mu) * rstd * gb.z + bb.z;  o1.w = (v1.w - mu) * rstd * gb.w + bb.w;
    ((float4*)(xlast + (size_t)b * DD))[tid]       = o0;
    ((float4*)(xlast + (size_t)b * DD))[tid + 256] = o1;
}

// ---------- init: dst[i] = bias[i % mod] (mod power of 2) ----------
__global__ __launch_bounds__(256) void k_init_bias(float* __restrict__ dst, const float* __restrict__ bias,
                                                   int n, int mod) {
    int i = blockIdx.x * 256 + threadIdx.x;
    if (i < n) dst[i] = bias[i & (mod - 1)];
}

// ---------- Kq: q[b,p] += sum_d xlast[b,d]*wq[d,p] ----------
__global__ __launch_bounds__(256) void k_q(const float* __restrict__ xlast, const float* __restrict__ wq,
                                           float* __restrict__ q) {
    int ptile = blockIdx.x, dch = blockIdx.y, tid = threadIdx.x;
    __shared__ float xs[16][256];
    #pragma unroll
    for (int k = 0; k < 4; k++) {
        int f4 = tid + k * 256;
        int b = f4 >> 6, c4 = f4 & 63;
        *(float4*)&xs[b][c4 * 4] = *(const float4*)&xlast[(size_t)b * DD + dch * 256 + c4 * 4];
    }
    __syncthreads();
    int p = ptile * 256 + tid;
    float acc[16];
    #pragma unroll
    for (int b = 0; b < 16; b++) acc[b] = 0.f;
    for (int dd = 0; dd < 256; dd++) {
        float wqv = wq[(size_t)(dch * 256 + dd) * DD + p];
        #pragma unroll
        for (int b = 0; b < 16; b++) acc[b] = fmaf(xs[b][dd], wqv, acc[b]);
    }
    #pragma unroll
    for (int b = 0; b < 16; b++) atomicAdd(&q[(size_t)b * DD + p], acc[b]);
}

// ---------- Kt: t[b,h,d] = sum_j wk[d, h*128+j]*q[b, h*128+j]; tg = t*g[d] ----------
__global__ __launch_bounds__(256) void k_t(const float* __restrict__ wk, const float* __restrict__ q,
                                           const float* __restrict__ g, float* __restrict__ t_out,
                                           float* __restrict__ tg_out) {
    int d = blockIdx.x, tid = threadIdx.x;
    __shared__ float wkl[16 * 132];
    #pragma unroll
    for (int k = 0; k < 2; k++) {
        int f4 = tid + k * 256;
        int h = f4 >> 5, j4 = f4 & 31;
        *(float4*)&wkl[h * 132 + j4 * 4] = *(const float4*)&wk[(size_t)d * DD + h * 128 + j4 * 4];
    }
    __syncthreads();
    int b = tid >> 4, h = tid & 15;
    const float4* q4 = (const float4*)(q + (size_t)b * DD + h * 128);
    float acc = 0.f;
    #pragma unroll
    for (int j4 = 0; j4 < 32; j4++) {
        float4 qv = q4[j4];
        float4 wv4 = *(const float4*)&wkl[h * 132 + j4 * 4];
        acc = fmaf(qv.x, wv4.x, fmaf(qv.y, wv4.y, fmaf(qv.z, wv4.z, fmaf(qv.w, wv4.w, acc))));
    }
    size_t o = (size_t)(b * 16 + h) * DD + d;
    t_out[o] = acc;
    tg_out[o] = acc * g[d];
}

// ---------- KG: G1[bh]=sum_d tg ; wconst[bh]=sum_d beta*t + sum_j bk*q ----------
__global__ __launch_bounds__(256) void k_G(const float* __restrict__ t_in, const float* __restrict__ tg_in,
                                           const float* __restrict__ q, const float* __restrict__ lnb,
                                           const float* __restrict__ bk, float* __restrict__ G1,
                                           float* __restrict__ wconst) {
    int bh = blockIdx.x, tid = threadIdx.x;
    int b = bh >> 4, h = bh & 15;
    __shared__ float s4[4];
    const float4* tg4 = (const float4*)(tg_in + (size_t)bh * DD);
    const float4* t4  = (const float4*)(t_in + (size_t)bh * DD);
    const float4* lb4 = (const float4*)lnb;
    float g1p = 0.f, g2p = 0.f;
    #pragma unroll
    for (int k = 0; k < 2; k++) {
        int f = tid + k * 256;
        float4 a = tg4[f];
        g1p += a.x + a.y + a.z + a.w;
        float4 tv = t4[f];
        float4 bv = lb4[f];
        g2p = fmaf(tv.x, bv.x, fmaf(tv.y, bv.y, fmaf(tv.z, bv.z, fmaf(tv.w, bv.w, g2p))));
    }
    float cp = 0.f;
    if (tid < 128) cp = bk[h * 128 + tid] * q[(size_t)b * DD + h * 128 + tid];
    float G1v = block_sum256(g1p, s4);
    float rest = block_sum256(g2p + cp, s4);
    if (tid == 0) { G1[bh] = G1v; wconst[bh] = rest; }
}

// ---------- K1: partial LN-stats + 16-head dots over a D-half.
// grid (B, S/32, 2). 256 thr: qd=tid&15 (d-slice), rg=tid>>4 (row pair).
// x: global->registers (2-deep prefetch). tg: LDS double-buffered, 1 barrier/chunk.
// writes part[b][dh][s][0..15]=raw dots, [16]=sum, [17]=ssq  (stride 20)
__global__ __launch_bounds__(256) void k_logits2(const float* __restrict__ hid, const float* __restrict__ tg,
                                                 float* __restrict__ part) {
    int b = blockIdx.x, st = blockIdx.y, dh = blockIdx.z;
    int tid = threadIdx.x, qd = tid & 15, rg = tid >> 4;
    __shared__ float tl[2][16][132];
    const int d0base = dh * 1024;
    const size_t rowbase = ((size_t)b * SS + st * 32 + rg * 2) * DD;

    float raw[2][16], sum[2], ssq[2];
    #pragma unroll
    for (int r = 0; r < 2; r++) {
        sum[r] = 0.f; ssq[r] = 0.f;
        #pragma unroll
        for (int h = 0; h < 16; h++) raw[r][h] = 0.f;
    }

    float4 xa[2][2], xb[2][2], ta[2], tb[2];

    // prologue: chunk 0
    {
        int d0 = d0base;
        #pragma unroll
        for (int k = 0; k < 2; k++) {
            int f = tid + k * 256; int h = f >> 5, c4 = f & 31;
            ta[k] = *(const float4*)&tg[(size_t)(b * 16 + h) * DD + d0 + c4 * 4];
        }
        #pragma unroll
        for (int rr = 0; rr < 2; rr++)
            #pragma unroll
            for (int k = 0; k < 2; k++)
                xa[rr][k] = *(const float4*)&hid[rowbase + (size_t)rr * DD + d0 + (qd + 16 * k) * 4];
        #pragma unroll
        for (int k = 0; k < 2; k++) {
            int f = tid + k * 256; int h = f >> 5, c4 = f & 31;
            *(float4*)&tl[0][h][c4 * 4] = ta[k];
        }
        __syncthreads();
    }

    auto do_chunk = [&](int c, int buf, float4 (&xc)[2][2], float4 (&xn)[2][2], float4 (&tn)[2], bool last) {
        if (!last) {
            int d0n = d0base + (c + 1) * 128;
            #pragma unroll
            for (int k = 0; k < 2; k++) {
                int f = tid + k * 256; int h = f >> 5, c4 = f & 31;
                tn[k] = *(const float4*)&tg[(size_t)(b * 16 + h) * DD + d0n + c4 * 4];
            }
            #pragma unroll
            for (int rr = 0; rr < 2; rr++)
                #pragma unroll
                for (int k = 0; k < 2; k++)
                    xn[rr][k] = *(const float4*)&hid[rowbase + (size_t)rr * DD + d0n + (qd + 16 * k) * 4];
        }
        #pragma unroll
        for (int k = 0; k < 2; k++) {
            float4 x0 = xc[0][k], x1 = xc[1][k];
            sum[0] += x0.x + x0.y + x0.z + x0.w;
            sum[1] += x1.x + x1.y + x1.z + x1.w;
            ssq[0] = fmaf(x0.x, x0.x, fmaf(x0.y, x0.y, fmaf(x0.z, x0.z, fmaf(x0.w, x0.w, ssq[0]))));
            ssq[1] = fmaf(x1.x, x1.x, fmaf(x1.y, x1.y, fmaf(x1.z, x1.z, fmaf(x1.w, x1.w, ssq[1]))));
            #pragma unroll
            for (int h = 0; h < 16; h++) {
                float4 tv = *(const float4*)&tl[buf][h][(qd + 16 * k) * 4];
                raw[0][h] = fmaf(x0.x, tv.x, fmaf(x0.y, tv.y, fmaf(x0.z, tv.z, fmaf(x0.w, tv.w, raw[0][h]))));
                raw[1][h] = fmaf(x1.x, tv.x, fmaf(x1.y, tv.y, fmaf(x1.z, tv.z, fmaf(x1.w, tv.w, raw[1][h]))));
            }
        }
        if (!last) {
            #pragma unroll
            for (int k = 0; k < 2; k++) {
                int f = tid + k * 256; int h = f >> 5, c4 = f & 31;
                *(float4*)&tl[buf ^ 1][h][c4 * 4] = tn[k];
            }
        }
        __syncthreads();
    };

    do_chunk(0, 0, xa, xb, tb, false);
    do_chunk(1, 1, xb, xa, ta, false);
    do_chunk(2, 0, xa, xb, tb, false);
    do_chunk(3, 1, xb, xa, ta, false);
    do_chunk(4, 0, xa, xb, tb, false);
    do_chunk(5, 1, xb, xa, ta, false);
    do_chunk(6, 0, xa, xb, tb, false);
    do_chunk(7, 1, xb, xa, ta, true);

    // butterfly reduce over the 16 qd lanes (lane bits 0..3)
    #pragma unroll
    for (int m = 1; m < 16; m <<= 1) {
        #pragma unroll
        for (int r = 0; r < 2; r++) {
            #pragma unroll
            for (int h = 0; h < 16; h++) raw[r][h] += __shfl_xor(raw[r][h], m, 64);
            sum[r] += __shfl_xor(sum[r], m, 64);
            ssq[r] += __shfl_xor(ssq[r], m, 64);
        }
    }
    #pragma unroll
    for (int rr = 0; rr < 2; rr++) {
        int s = st * 32 + rg * 2 + rr;
        float* p = part + ((size_t)(b * 2 + dh) * SS + s) * 20;
        p[qd] = raw[rr][qd];
        if (qd == 0) { p[16] = sum[rr]; p[17] = ssq[rr]; }
    }
}

// ---------- K1b: combine D-halves, finish LN stats, emit logits ----------
__global__ __launch_bounds__(256) void k_lfix(const float* __restrict__ part, const float* __restrict__ G1,
                                              const float* __restrict__ wcst, float* __restrict__ wout,
                                              float* __restrict__ muA, float* __restrict__ rsA) {
    int b = blockIdx.x;
    int s = blockIdx.y * 256 + threadIdx.x;
    const float* p0 = part + ((size_t)(b * 2 + 0) * SS + s) * 20;
    const float* p1 = part + ((size_t)(b * 2 + 1) * SS + s) * 20;
    float sum = p0[16] + p1[16], ssq = p0[17] + p1[17];
    float mu = sum * (1.0f / DD);
    float rstd = rsqrtf(ssq * (1.0f / DD) - mu * mu + LN_EPS);
    muA[(size_t)b * SS + s] = mu;
    rsA[(size_t)b * SS + s] = rstd;
    #pragma unroll
    for (int h = 0; h < 16; h++) {
        float raw = p0[h] + p1[h];
        wout[(size_t)(b * 16 + h) * SS + s] = rstd * (raw - mu * G1[b * 16 + h]) + wcst[b * 16 + h];
    }
}

// ---------- K2: softmax over s per (b,h); coef = p*rstd; M = sum coef*mu ----------
__global__ __launch_bounds__(256) void k_softmax(const float* __restrict__ wlog, const float* __restrict__ muA,
                                                 const float* __restrict__ rsA, float* __restrict__ coef,
                                                 float* __restrict__ Mout) {
    int bh = blockIdx.x, tid = threadIdx.x;
    int b = bh >> 4;
    __shared__ float s4[4];
    const float4* w4 = (const float4*)(wlog + (size_t)bh * SS);
    float4 v0 = w4[tid], v1 = w4[tid + 256];
    float mx = fmaxf(fmaxf(fmaxf(v0.x, v0.y), fmaxf(v0.z, v0.w)),
                     fmaxf(fmaxf(v1.x, v1.y), fmaxf(v1.z, v1.w)));
    mx = block_max256(mx, s4);
    float4 e0, e1;
    e0.x = __expf(v0.x - mx); e0.y = __expf(v0.y - mx); e0.z = __expf(v0.z - mx); e0.w = __expf(v0.w - mx);
    e1.x = __expf(v1.x - mx); e1.y = __expf(v1.y - mx); e1.z = __expf(v1.z - mx); e1.w = __expf(v1.w - mx);
    float ssum = e0.x + e0.y + e0.z + e0.w + e1.x + e1.y + e1.z + e1.w;
    ssum = block_sum256(ssum, s4);
    float inv = 1.0f / ssum;
    const float4* r4 = (const float4*)(rsA + (size_t)b * SS);
    const float4* m4 = (const float4*)(muA + (size_t)b * SS);
    float4 ra = r4[tid], rb = r4[tid + 256], ma = m4[tid], mb = m4[tid + 256];
    float4 c0, c1;
    c0.x = e0.x * inv * ra.x; c0.y = e0.y * inv * ra.y; c0.z = e0.z * inv * ra.z; c0.w = e0.w * inv * ra.w;
    c1.x = e1.x * inv * rb.x; c1.y = e1.y * inv * rb.y; c1.z = e1.z * inv * rb.z; c1.w = e1.w * inv * rb.w;
    ((float4*)(coef + (size_t)bh * SS))[tid] = c0;
    ((float4*)(coef + (size_t)bh * SS))[tid + 256] = c1;
    float Mp = c0.x * ma.x + c0.y * ma.y + c0.z * ma.z + c0.w * ma.w
             + c1.x * mb.x + c1.y * mb.y + c1.z * mb.z + c1.w * mb.w;
    Mp = block_sum256(Mp, s4);
    if (tid == 0) Mout[bh] = Mp;
}

// ---------- K3: Apart[ch][b][h][d] = sum_{s in chunk} coef*hid.
// grid (B, 4 dtiles, 16 schunks). thread owns float2 column, 4-deep prefetch.
__global__ __launch_bounds__(256) void k_pv2(const float* __restrict__ hid, const float* __restrict__ coef,
                                             float* __restrict__ Apart) {
    int b = blockIdx.x, dt = blockIdx.y, ch = blockIdx.z, tid = threadIdx.x;
    __shared__ float cl[128][20];
    int s0 = ch * 128;
    #pragma unroll
    for (int k = 0; k < 2; k++) {
        int f = tid + k * 256; int h = f >> 5, s4i = f & 31;
        float4 c4 = *(const float4*)&coef[(size_t)(b * 16 + h) * SS + s0 + s4i * 4];
        cl[s4i * 4 + 0][h] = c4.x; cl[s4i * 4 + 1][h] = c4.y;
        cl[s4i * 4 + 2][h] = c4.z; cl[s4i * 4 + 3][h] = c4.w;
    }
    __syncthreads();
    int d = dt * 512 + tid * 2;
    const float* hb = hid + ((size_t)b * SS + s0) * DD + d;
    float2 acc[16];
    #pragma unroll
    for (int h = 0; h < 16; h++) acc[h] = make_float2(0.f, 0.f);
    float2 xv[4];
    #pragma unroll
    for (int i = 0; i < 4; i++) xv[i] = *(const float2*)(hb + (size_t)i * DD);
    #pragma unroll 1
    for (int sb = 0; sb < 32; sb++) {
        #pragma unroll
        for (int i = 0; i < 4; i++) {
            int s = sb * 4 + i;
            float2 x = xv[i];
            if (sb < 31) xv[i] = *(const float2*)(hb + (size_t)(s + 4) * DD);
            const float* cs = &cl[s][0];
            #pragma unroll
            for (int h = 0; h < 16; h++) {
                float c = cs[h];
                acc[h].x = fmaf(c, x.x, acc[h].x);
                acc[h].y = fmaf(c, x.y, acc[h].y);
            }
        }
    }
    #pragma unroll
    for (int h = 0; h < 16; h++)
        *(float2*)&Apart[((size_t)(ch * 16 + b) * 16 + h) * DD + d] = acc[h];
}

// ---------- K3b: A = sum over 16 chunks of Apart ----------
__global__ __launch_bounds__(256) void k_red(const float* __restrict__ Apart, float* __restrict__ A) {
    size_t i4 = (size_t)blockIdx.x * 256 + threadIdx.x;
    const float4* ap = (const float4*)Apart;
    float4 acc = make_float4(0.f, 0.f, 0.f, 0.f);
    #pragma unroll
    for (int c = 0; c < 16; c++) {
        float4 v = ap[(size_t)c * 131072 + i4];
        acc.x += v.x; acc.y += v.y; acc.z += v.z; acc.w += v.w;
    }
    ((float4*)A)[i4] = acc;
}

// ---------- K4a: attn[b, h*128+j] += sum_d y[b,h,d]*wv[d, h*128+j] ----------
__global__ __launch_bounds__(256) void k_attnv(const float* __restrict__ A, const float* __restrict__ M,
                                               const float* __restrict__ g, const float* __restrict__ be,
                                               const float* __restrict__ wv, float* __restrict__ attn) {
    int h = blockIdx.x, dc = blockIdx.y, tid = threadIdx.x;
    __shared__ float yl[16][128];
    int d0 = dc * 128;
    #pragma unroll
    for (int k = 0; k < 2; k++) {
        int f4 = tid + k * 256;
        int b = f4 >> 5, c4 = f4 & 31;
        float4 a4 = *(const float4*)&A[(size_t)(b * 16 + h) * DD + d0 + c4 * 4];
        float4 g4 = *(const float4*)&g[d0 + c4 * 4];
        float4 b4 = *(const float4*)&be[d0 + c4 * 4];
        float m = M[b * 16 + h];
        float4 y;
        y.x = g4.x * (a4.x - m) + b4.x;  y.y = g4.y * (a4.y - m) + b4.y;
        y.z = g4.z * (a4.z - m) + b4.z;  y.w = g4.w * (a4.w - m) + b4.w;
        *(float4*)&yl[b][c4 * 4] = y;
    }
    __syncthreads();
    int j = tid & 127, h2 = tid >> 7;
    float acc[16];
    #pragma unroll
    for (int b = 0; b < 16; b++) acc[b] = 0.f;
    for (int dl = 0; dl < 64; dl++) {
        int dd = h2 * 64 + dl;
        float wvv = wv[(size_t)(d0 + dd) * DD + h * 128 + j];
        #pragma unroll
        for (int b = 0; b < 16; b++) acc[b] = fmaf(yl[b][dd], wvv, acc[b]);
    }
    #pragma unroll
    for (int b = 0; b < 16; b++) atomicAdd(&attn[(size_t)b * DD + h * 128 + j], acc[b]);
}

// ---------- K4b: out[b,p] += sum_c attn[b,c]*wo[c,p] ----------
__global__ __launch_bounds__(256) void k_out(const float* __restrict__ attn, const float* __restrict__ wo,
                                             float* __restrict__ out) {
    int ptile = blockIdx.x, cch = blockIdx.y, tid = threadIdx.x;
    __shared__ float al[16][128];
    int c0 = cch * 128;
    #pragma unroll
    for (int k = 0; k < 2; k++) {
        int f4 = tid + k * 256;
        int b = f4 >> 5, c4 = f4 & 31;
        *(float4*)&al[b][c4 * 4] = *(const float4*)&attn[(size_t)b * DD + c0 + c4 * 4];
    }
    __syncthreads();
    int p = ptile * 256 + tid;
    float acc[16];
    #pragma unroll
    for (int b = 0; b < 16; b++) acc[b] = 0.f;
    for (int cc = 0; cc < 128; cc++) {
        float wov = wo[(size_t)(c0 + cc) * DD + p];
        #pragma unroll
        for (int b = 0; b < 16; b++) acc[b] = fmaf(al[b][cc], wov, acc[b]);
    }
    #pragma unroll
    for (int b = 0; b < 16; b++) atomicAdd(&out[(size_t)b * DD + p], acc[b]);
}

extern "C" void kernel_launch(void* const* d_in, const int* in_sizes, int n_in,
                              void* d_out, int out_size, void* d_ws, size_t ws_size,
                              hipStream_t stream) {
    const float* hid = (const float*)d_in[0];
    const int*   ids = (const int*)d_in[1];
    const float* lnw = (const float*)d_in[2];
    const float* lnb = (const float*)d_in[3];
    const float* wq  = (const float*)d_in[4];
    const float* bq  = (const float*)d_in[5];
    const float* wk  = (const float*)d_in[6];
    const float* bk  = (const float*)d_in[7];
    const float* wv  = (const float*)d_in[8];
    const float* bv  = (const float*)d_in[9];
    const float* wo  = (const float*)d_in[10];
    const float* bo  = (const float*)d_in[11];
    float* out = (float*)d_out;

    float* ws = (float*)d_ws;
    int*   idx   = (int*)ws;                     // 16
    float* xlast = ws + 16;                      // 32768
    float* q     = xlast + 32768;                // 32768
    float* t     = q + 32768;                    // 524288
    float* tg    = t + 524288;                   // 524288
    float* G1    = tg + 524288;                  // 256
    float* wcst  = G1 + 256;                     // 256
    float* wlog  = wcst + 256;                   // 524288
    float* muA   = wlog + 524288;                // 32768
    float* rsA   = muA + 32768;                  // 32768
    float* coef  = rsA + 32768;                  // 524288
    float* Mbh   = coef + 524288;                // 256
    float* Abh   = Mbh + 256;                    // 524288
    float* attn  = Abh + 524288;                 // 32768
    float* Apart = attn + 32768;                 // 8388608
    float* part  = Apart + 8388608;              // 16*2*2048*20 = 1310720

    k_idx<<<16, 256, 0, stream>>>(ids, idx);
    k_xlast<<<16, 256, 0, stream>>>(hid, idx, lnw, lnb, xlast);
    k_init_bias<<<128, 256, 0, stream>>>(q, bq, 32768, DD);
    k_q<<<dim3(8, 8), 256, 0, stream>>>(xlast, wq, q);
    k_t<<<2048, 256, 0, stream>>>(wk, q, lnw, t, tg);
    k_G<<<256, 256, 0, stream>>>(t, tg, q, lnb, bk, G1, wcst);
    k_logits2<<<dim3(16, 64, 2), 256, 0, stream>>>(hid, tg, part);
    k_lfix<<<dim3(16, 8), 256, 0, stream>>>(part, G1, wcst, wlog, muA, rsA);
    k_softmax<<<256, 256, 0, stream>>>(wlog, muA, rsA, coef, Mbh);
    k_pv2<<<dim3(16, 4, 16), 256, 0, stream>>>(hid, coef, Apart);
    k_red<<<512, 256, 0, stream>>>(Apart, Abh);
    k_init_bias<<<128, 256, 0, stream>>>(attn, bv, 32768, DD);
    k_attnv<<<dim3(16, 16), 256, 0, stream>>>(Abh, Mbh, lnw, lnb, wv, attn);
    k_init_bias<<<128, 256, 0, stream>>>(out, bo, 32768, DD);
    k_out<<<dim3(8, 16), 256, 0, stream>>>(attn, wo, out);
}